// Round 4
// baseline (342.479 us; speedup 1.0000x reference)
//
#include <hip/hip_runtime.h>
#include <math.h>

#define B_      16
#define K_      200000
#define N_      40
#define TPB     256
#define ITEMS   2
#define TILE    (TPB * ITEMS)                 // 512 elements per block
#define NBX     ((K_ + TILE - 1) / TILE)      // 391
#define NBLOCKS (NBX * B_)                    // 6256
#define NE      (2 * N_)                      // 80 endpoints
#define NACC    7                             // live accumulators
#define PACC    8                             // padded storage stride (8B-pair loads)

// ws layout:
//   [0, PART_BYTES)            : per-block partials (NBLOCKS x PACC floats, q=7 pad)
//   [TBL_OFF + b*TBL_STRIDE..) : per-batch tables:
//       float  bp[80]   @ +0     sorted endpoints
//       float4 at4[80]  @ +320   (tl,tr,lab,valid) winner when c == bp[i]
//       float4 gap4[81] @ +1600  (tl,tr,lab,valid) winner for open gap (bp[i-1],bp[i])
//   [CNT_OFF]                  : int done-counter (zeroed by msl_setup)
#define PART_BYTES  (NBLOCKS * PACC * 4)      // 200,192
#define TBL_OFF     PART_BYTES
#define TBL_STRIDE  3072
#define CNT_OFF     (TBL_OFF + B_ * TBL_STRIDE)   // 249,344; ws use 249,348 B

// async global->LDS DMA, 16B per active lane, no VGPR round-trip (m97 pattern)
__device__ __forceinline__ void gload16(const float4* g, float4* l) {
    __builtin_amdgcn_global_load_lds(
        (const __attribute__((address_space(1))) unsigned int*)g,
        (__attribute__((address_space(3))) unsigned int*)l,
        16, 0, 0);
}

__global__ __launch_bounds__(256) void msl_setup(
    const float* __restrict__ targets, char* __restrict__ ws)
{
    __shared__ float tl0[N_], tr0[N_], lb0[N_], ar0[N_];
    __shared__ float stl[N_], str[N_], slb[N_];
    __shared__ float ep[NE], bp[NE];
    const int b = blockIdx.x, t = threadIdx.x;

    if (b == 0 && t == 0) *(int*)(ws + CNT_OFF) = 0;   // done-counter init

    if (t < N_) {
        const float* tg = targets + (b * N_ + t) * 3;
        const float tl = tg[0], tr = tg[1];
        tl0[t] = tl; tr0[t] = tr; lb0[t] = tg[2];
        ar0[t] = (tr - tl) * 256.0f;
    }
    __syncthreads();

    // stable rank-sort segments by area (tie: original index) -> priority order
    if (t < N_) {
        const float an = ar0[t];
        int r = 0;
        #pragma unroll
        for (int m = 0; m < N_; ++m) {
            const float am = ar0[m];
            r += (am < an) || (am == an && m < t);
        }
        stl[r] = tl0[t]; str[r] = tr0[t]; slb[r] = lb0[t];
    }
    if (t < NE) ep[t] = (t < N_) ? tl0[t] : tr0[t - N_];
    __syncthreads();

    // rank-sort endpoints
    if (t < NE) {
        const float v = ep[t];
        int r = 0;
        #pragma unroll
        for (int m = 0; m < NE; ++m) {
            const float vm = ep[m];
            r += (vm < v) || (vm == v && m < t);
        }
        bp[r] = v;
    }
    __syncthreads();

    char* tb = ws + TBL_OFF + b * TBL_STRIDE;

    // point winners: first (priority-order) segment with stl<=v<=str
    if (t < NE) {
        const float v = bp[t];
        int w = N_;
        for (int s = N_ - 1; s >= 0; --s)
            w = (stl[s] <= v && v <= str[s]) ? s : w;
        const bool ok = (w < N_);
        const int si = ok ? w : 0;
        ((float4*)(tb + 320))[t] = ok
            ? make_float4(stl[si], str[si], slb[si], 1.0f)
            : make_float4(0.f, 0.f, 0.f, 0.f);
        ((float*)tb)[t] = v;
    }
    // gap winners: open interval (a, bb) entirely inside [stl, str]
    if (t >= 128 && t < 128 + NE + 1) {
        const int g = t - 128;                 // 0..80
        const float a  = g ? bp[g - 1] : -INFINITY;
        const float bb = (g < NE) ? bp[g] : INFINITY;
        int w = N_;
        for (int s = N_ - 1; s >= 0; --s)
            w = (stl[s] <= a && bb <= str[s]) ? s : w;
        const bool ok = (w < N_);
        const int si = ok ? w : 0;
        ((float4*)(tb + 1600))[g] = ok
            ? make_float4(stl[si], str[si], slb[si], 1.0f)
            : make_float4(0.f, 0.f, 0.f, 0.f);
    }
}

__device__ __forceinline__ void elem_accum(
    const float c, const float pl, const float pr,
    const float x0, const float x1,
    const float p0, const float p1,
    const float y0, const float y1,
    const float lg,
    const int base, const int end,
    const float* __restrict__ s_bp,
    const float4* __restrict__ s_tab,          // [0..79]=at, [80..160]=gap
    float& f0, float& f1, float& f2, float& f3,
    float& f4, float& f5, float& f6)
{
    const float EPS = 1.1920928955078125e-7f;  // FLT_EPSILON

    // ---- match: pos = #bp <= c; in-range bp are contiguous [base,end) ----
    int pos = base; bool eq = false;
    for (int i = base; i < end; ++i) {           // block-uniform bounds
        const float v = s_bp[i];                 // broadcast read
        pos += (v <= c) ? 1 : 0;
        eq  |= (v == c);
    }
    const int idx = eq ? (pos - 1) : (NE + pos);
    const float4 sg = s_tab[idx];

    const float tl = sg.x, tr = sg.y;
    const int conf_t = (int)sg.z;                // 0 when unmatched
    const float lt0 = (c - tl) * 256.0f;
    const float lt1 = (tr - c) * 256.0f;

    // ---- iou(loc, loc_t) ----
    const float inter = fminf(pl, lt0) + fminf(pr, lt1);
    const float uni   = pl + pr + (lt0 + lt1) - inter;
    const float iou   = __fdividef(inter, fmaxf(uni, EPS));
    const int pconf_t = (iou < 0.5f) ? 0 : conf_t;

    const float posf = (conf_t > 0) ? 1.0f : 0.0f;
    const float ppf  = (pconf_t > 0) ? 1.0f : 0.0f;

    // GIoU (pos only)
    const float ac   = fmaxf(pl, lt0) + fmaxf(pr, lt1);
    const float giou = iou - __fdividef(ac - uni, fmaxf(ac, EPS));
    f0 += (1.0f - giou) * posf;

    // prop loc L1 (prop-pos only)
    const float prop_w = pl + pr;
    const float rw = __fdividef(1.0f, 0.5f * prop_w);
    const float plt0 = (lt0 - pl) * rw;
    const float plt1 = (lt1 - pr) * rw;
    f2 += (fabsf(p0 - plt0) + fabsf(p1 - plt1)) * ppf;

    // centerness BCE (pos only)
    const float cur0 = 0.5f * prop_w * p0 + pl;
    const float cur1 = 0.5f * prop_w * p1 + pr;
    const float inter2 = fminf(cur0, lt0) + fminf(cur1, lt1);
    const float uni2   = cur0 + cur1 + (lt0 + lt1) - inter2;
    const float iou2   = fmaxf(__fdividef(inter2, fmaxf(uni2, EPS)), 0.0f);
    const float bce = fmaxf(lg, 0.0f) - lg * iou2
                      + __logf(1.0f + __expf(-fabsf(lg)));
    f4 += bce * posf;

    // focal on conf (all elements)
    {
        const float xt = conf_t ? x1 : x0;
        const float xo = conf_t ? x0 : x1;
        const float pt = __fdividef(1.0f, 1.0f + __expf(xo - xt)) + 1e-6f;
        const float al = conf_t ? 0.75f : 0.25f;
        const float om = 1.0f - pt;
        f1 += -om * om * al * __logf(pt);
    }
    // focal on prop_conf (all elements)
    {
        const float xt = pconf_t ? y1 : y0;
        const float xo = pconf_t ? y0 : y1;
        const float pt = __fdividef(1.0f, 1.0f + __expf(xo - xt)) + 1e-6f;
        const float al = pconf_t ? 0.75f : 0.25f;
        const float om = 1.0f - pt;
        f3 += -om * om * al * __logf(pt);
    }

    f5 += posf;
    f6 += ppf;
}

__global__ __launch_bounds__(TPB) void msl_main(
    const float* __restrict__ loc,     // (B,K,2)
    const float* __restrict__ conf,    // (B,K,2)
    const float* __restrict__ ploc,    // (B,K,2)
    const float* __restrict__ pconf,   // (B,K,2)
    const float* __restrict__ center,  // (B,K,1)
    const float* __restrict__ priors,  // (K,1)
    char* __restrict__ ws,
    float* __restrict__ out)
{
    // staging: [0,256)=loc [256,512)=conf [512,768)=ploc [768,1024)=pconf
    //          [1024,1152)=center [1152,1280)=priors   (float4 units, 20 KB)
    __shared__ float4 s_stage[1280];
    __shared__ float  s_bp[NE];
    __shared__ float4 s_tab[2 * NE + 1];   // [0..79]=at, [80..160]=gap
    __shared__ int    s_cnt[4];            // {base_w0, base_w1, end_w0, end_w1}
    __shared__ float  s_redf[TPB / 64][NACC];
    __shared__ int    s_last;

    const int b = blockIdx.y;
    const int t = threadIdx.x;
    const int kb = blockIdx.x * TILE;
    const int kend = (kb + TILE < K_) ? kb + TILE : K_;
    const int nval = kend - kb;            // 512 (full) or 320 (tail)
    const int nc2  = nval >> 1;            // 16B chunks per (B,K,2) slice
    const int nc4  = nval >> 2;            // 16B chunks per (B,K,1) slice

    const int bK  = b * K_;
    const int bK2 = bK * 2;

    // ---- issue ALL staging DMAs first (async, zero VGPR results) ----
    {
        const float4* g0 = (const float4*)(loc   + bK2 + kb * 2);
        const float4* g1 = (const float4*)(conf  + bK2 + kb * 2);
        const float4* g2 = (const float4*)(ploc  + bK2 + kb * 2);
        const float4* g3 = (const float4*)(pconf + bK2 + kb * 2);
        if (t < nc2) {
            gload16(g0 + t, s_stage +        t);
            gload16(g1 + t, s_stage +  256 + t);
            gload16(g2 + t, s_stage +  512 + t);
            gload16(g3 + t, s_stage +  768 + t);
        }
        if (t < 128) {
            if (t < nc4)
                gload16((const float4*)(center + bK + kb) + t, s_stage + 1024 + t);
        } else {
            const int u = t - 128;
            if (u < nc4)
                gload16((const float4*)(priors + kb) + u, s_stage + 1152 + u);
        }
    }

    // ---- table loads + ballot counts (overlap with staging DMA) ----
    {
        const char* tb = ws + TBL_OFF + b * TBL_STRIDE;
        if (t < 128) {
            const float v = (t < NE) ? ((const float*)tb)[t] : INFINITY;
            if (t < NE) s_bp[t] = v;
            const float cmin = priors[kb];          // uniform
            const float cmax = priors[kend - 1];
            const unsigned long long mlo = __ballot(v < cmin);
            const unsigned long long mhi = __ballot(v <= cmax);
            const int wv = t >> 6;                   // 0 or 1
            if ((t & 63) == 0) {
                s_cnt[wv]     = __popcll(mlo);
                s_cnt[2 + wv] = __popcll(mhi);
            }
        } else if (t < 208) {                        // 80 at4 -> s_tab[0..79]
            s_tab[t - 128] = ((const float4*)(tb + 320))[t - 128];
        } else {                                     // gap4[0..47]
            s_tab[NE + (t - 208)] = ((const float4*)(tb + 1600))[t - 208];
        }
        if (t < 33)                                  // gap4[48..80]
            s_tab[NE + 48 + t] = ((const float4*)(tb + 1600))[48 + t];
    }
    __syncthreads();   // drains vmcnt (staging DMAs) + lgkm (table writes)

    const int base = s_cnt[0] + s_cnt[1];            // #bp <  cmin
    const int end  = s_cnt[2] + s_cnt[3];            // #bp <= cmax

    float f0 = 0.f, f1 = 0.f, f2 = 0.f, f3 = 0.f, f4 = 0.f, f5 = 0.f, f6 = 0.f;

    // ---- compute: pure LDS reads, low pipelinable latency ----
    {
        const float2* l2p = (const float2*)(s_stage);
        const float2* c2p = (const float2*)(s_stage +  256);
        const float2* p2p = (const float2*)(s_stage +  512);
        const float2* q2p = (const float2*)(s_stage +  768);
        const float*  ctp = (const float*)(s_stage + 1024);
        const float*  prp = (const float*)(s_stage + 1152);
        #pragma unroll
        for (int j = 0; j < ITEMS; ++j) {
            const int kl = t + j * TPB;
            if (kl < nval) {
                const float2 l  = l2p[kl];
                const float2 cf = c2p[kl];
                const float2 pp = p2p[kl];
                const float2 pc = q2p[kl];
                elem_accum(prp[kl], l.x, l.y, cf.x, cf.y,
                           pp.x, pp.y, pc.x, pc.y, ctp[kl],
                           base, end, s_bp, s_tab,
                           f0, f1, f2, f3, f4, f5, f6);
            }
        }
    }

    // ---- block reduction (f32 wave tree, f64 cross-wave) -> partials ----
    {
        float vals[NACC] = {f0, f1, f2, f3, f4, f5, f6};
        const int wave = t >> 6, lane = t & 63;
        #pragma unroll
        for (int q = 0; q < NACC; ++q) {
            float v = vals[q];
            #pragma unroll
            for (int off = 32; off > 0; off >>= 1)
                v += __shfl_down(v, off, 64);
            if (lane == 0) s_redf[wave][q] = v;
        }
    }
    __syncthreads();
    if (t == 0) {
        float* partials = (float*)ws;
        const int bid = blockIdx.y * gridDim.x + blockIdx.x;
        #pragma unroll
        for (int q = 0; q < NACC; ++q) {
            double s = 0.0;
            #pragma unroll
            for (int w2 = 0; w2 < TPB / 64; ++w2) s += (double)s_redf[w2][q];
            partials[bid * PACC + q] = (float)s;
        }
        __threadfence();                               // release partials
        const int old = atomicAdd((int*)(ws + CNT_OFF), 1);   // device scope
        s_last = (old == NBLOCKS - 1) ? 1 : 0;
    }
    __syncthreads();

    // ---- last block: final reduction (deterministic order) ----
    if (s_last) {
        __threadfence();                               // acquire
        const float* partials = (const float*)ws;
        double acc[NACC] = {0, 0, 0, 0, 0, 0, 0};
        for (int i = t; i < NBLOCKS; i += TPB) {
            const float* row = partials + (i << 3);    // PACC==8, 32B-aligned
            // AGENT-scope loads bypass non-coherent per-XCD L2
            const unsigned long long u01 = __hip_atomic_load(
                (const unsigned long long*)(row + 0), __ATOMIC_RELAXED, __HIP_MEMORY_SCOPE_AGENT);
            const unsigned long long u23 = __hip_atomic_load(
                (const unsigned long long*)(row + 2), __ATOMIC_RELAXED, __HIP_MEMORY_SCOPE_AGENT);
            const unsigned long long u45 = __hip_atomic_load(
                (const unsigned long long*)(row + 4), __ATOMIC_RELAXED, __HIP_MEMORY_SCOPE_AGENT);
            const float p6 = __hip_atomic_load(
                row + 6, __ATOMIC_RELAXED, __HIP_MEMORY_SCOPE_AGENT);
            const float2 p01 = __builtin_bit_cast(float2, u01);
            const float2 p23 = __builtin_bit_cast(float2, u23);
            const float2 p45 = __builtin_bit_cast(float2, u45);
            acc[0] += (double)p01.x; acc[1] += (double)p01.y;
            acc[2] += (double)p23.x; acc[3] += (double)p23.y;
            acc[4] += (double)p45.x; acc[5] += (double)p45.y;
            acc[6] += (double)p6;
        }
        __shared__ double s_fin[TPB / 64][NACC];
        const int wave = t >> 6, lane = t & 63;
        #pragma unroll
        for (int q = 0; q < NACC; ++q) {
            double v = acc[q];
            #pragma unroll
            for (int off = 32; off > 0; off >>= 1)
                v += __shfl_down(v, off, 64);
            if (lane == 0) s_fin[wave][q] = v;
        }
        __syncthreads();
        if (t == 0) {
            double s[NACC];
            #pragma unroll
            for (int q = 0; q < NACC; ++q) {
                double v = 0.0;
                #pragma unroll
                for (int w = 0; w < TPB / 64; ++w) v += s_fin[w][q];
                s[q] = v;
            }
            const double Np = fmax(s[5], 1.0);
            const double PN = fmax(s[6], 1.0);
            out[0] = (float)(s[0] / Np);
            out[1] = (float)(s[1] / Np);
            out[2] = (float)(s[2] / PN);
            out[3] = (float)(s[3] / PN);
            out[4] = (float)(s[4] / Np);
        }
    }
}

extern "C" void kernel_launch(void* const* d_in, const int* in_sizes, int n_in,
                              void* d_out, int out_size, void* d_ws, size_t ws_size,
                              hipStream_t stream) {
    const float* loc     = (const float*)d_in[0];
    const float* conf    = (const float*)d_in[1];
    const float* ploc    = (const float*)d_in[2];
    const float* pconf   = (const float*)d_in[3];
    const float* center  = (const float*)d_in[4];
    const float* priors  = (const float*)d_in[5];
    const float* targets = (const float*)d_in[6];
    char* ws = (char*)d_ws;   // uses 249,348 bytes

    msl_setup<<<B_, 256, 0, stream>>>(targets, ws);
    dim3 grid(NBX, B_);
    msl_main<<<grid, TPB, 0, stream>>>(loc, conf, ploc, pconf, center, priors,
                                       ws, (float*)d_out);
}

// Round 5
// 153.836 us; speedup vs baseline: 2.2263x; 2.2263x over previous
//
#include <hip/hip_runtime.h>
#include <math.h>

#define B_      16
#define K_      200000
#define N_      40
#define TPB     256
#define CBX     128                          // chunks per batch
#define CHUNK   ((K_ + CBX - 1) / CBX)       // 1563 contiguous priors per block
#define NITER   ((CHUNK + TPB - 1) / TPB)    // 7 strided iterations per thread
#define NBLOCKS (CBX * B_)                   // 2048 (= 8 blocks/CU exactly)
#define NE      (2 * N_)                     // 80 endpoints
#define NACC    7                            // live accumulators
#define PACC    8                            // padded partials stride

// ws: [0, NBLOCKS*PACC*4) per-block partials (65,536 B). Nothing else.

__device__ __forceinline__ void elem_accum(
    const float c, const float pl, const float pr,
    const float x0, const float x1,
    const float p0, const float p1,
    const float y0, const float y1,
    const float lg,
    const int base, const int end,
    const float* __restrict__ s_bp,
    const float4* __restrict__ s_tab,          // [0..79]=at, [80..160]=gap
    float& f0, float& f1, float& f2, float& f3,
    float& f4, float& f5, float& f6)
{
    const float EPS = 1.1920928955078125e-7f;  // FLT_EPSILON

    // ---- match: pos = #bp <= c; in-range bp are contiguous [base,end) ----
    int pos = base; bool eq = false;
    for (int i = base; i < end; ++i) {           // block-uniform bounds
        const float v = s_bp[i];                 // broadcast read
        pos += (v <= c) ? 1 : 0;
        eq  |= (v == c);
    }
    const int idx = eq ? (pos - 1) : (NE + pos);
    const float4 sg = s_tab[idx];

    const float tl = sg.x, tr = sg.y;
    const int conf_t = (int)sg.z;                // 0 when unmatched
    const float lt0 = (c - tl) * 256.0f;
    const float lt1 = (tr - c) * 256.0f;

    // ---- iou(loc, loc_t) ----
    const float inter = fminf(pl, lt0) + fminf(pr, lt1);
    const float uni   = pl + pr + (lt0 + lt1) - inter;
    const float iou   = __fdividef(inter, fmaxf(uni, EPS));
    const int pconf_t = (iou < 0.5f) ? 0 : conf_t;

    const float posf = (conf_t > 0) ? 1.0f : 0.0f;
    const float ppf  = (pconf_t > 0) ? 1.0f : 0.0f;

    // GIoU (pos only)
    const float ac   = fmaxf(pl, lt0) + fmaxf(pr, lt1);
    const float giou = iou - __fdividef(ac - uni, fmaxf(ac, EPS));
    f0 += (1.0f - giou) * posf;

    // prop loc L1 (prop-pos only)
    const float prop_w = pl + pr;
    const float rw = __fdividef(1.0f, 0.5f * prop_w);
    const float plt0 = (lt0 - pl) * rw;
    const float plt1 = (lt1 - pr) * rw;
    f2 += (fabsf(p0 - plt0) + fabsf(p1 - plt1)) * ppf;

    // centerness BCE (pos only)
    const float cur0 = 0.5f * prop_w * p0 + pl;
    const float cur1 = 0.5f * prop_w * p1 + pr;
    const float inter2 = fminf(cur0, lt0) + fminf(cur1, lt1);
    const float uni2   = cur0 + cur1 + (lt0 + lt1) - inter2;
    const float iou2   = fmaxf(__fdividef(inter2, fmaxf(uni2, EPS)), 0.0f);
    const float bce = fmaxf(lg, 0.0f) - lg * iou2
                      + __logf(1.0f + __expf(-fabsf(lg)));
    f4 += bce * posf;

    // focal on conf (all elements)
    {
        const float xt = conf_t ? x1 : x0;
        const float xo = conf_t ? x0 : x1;
        const float pt = __fdividef(1.0f, 1.0f + __expf(xo - xt)) + 1e-6f;
        const float al = conf_t ? 0.75f : 0.25f;
        const float om = 1.0f - pt;
        f1 += -om * om * al * __logf(pt);
    }
    // focal on prop_conf (all elements)
    {
        const float xt = pconf_t ? y1 : y0;
        const float xo = pconf_t ? y0 : y1;
        const float pt = __fdividef(1.0f, 1.0f + __expf(xo - xt)) + 1e-6f;
        const float al = pconf_t ? 0.75f : 0.25f;
        const float om = 1.0f - pt;
        f3 += -om * om * al * __logf(pt);
    }

    f5 += posf;
    f6 += ppf;
}

__global__ __launch_bounds__(TPB) void msl_main(
    const float* __restrict__ loc,     // (B,K,2)
    const float* __restrict__ conf,    // (B,K,2)
    const float* __restrict__ ploc,    // (B,K,2)
    const float* __restrict__ pconf,   // (B,K,2)
    const float* __restrict__ center,  // (B,K,1)
    const float* __restrict__ priors,  // (K,1)
    const float* __restrict__ targets, // (B,N,3)
    char* __restrict__ ws)
{
    __shared__ float  tl0[N_], tr0[N_], lb0[N_], ar0[N_];
    __shared__ float  stl[N_], str[N_], slb[N_];
    __shared__ float  s_ep[NE];
    __shared__ float  s_bp[NE];
    __shared__ float4 s_tab[2 * NE + 1];   // [0..79]=at, [80..160]=gap
    __shared__ int    s_cnt[4];            // {base_w0, base_w1, end_w0, end_w1}
    __shared__ float  s_redf[TPB / 64][NACC];

    const int b  = blockIdx.y;
    const int cb = blockIdx.x;
    const int t  = threadIdx.x;
    const int kb = cb * CHUNK;
    const int kend = (kb + CHUNK < K_) ? kb + CHUNK : K_;

    // ======== inline per-batch table construction (was msl_setup) ========
    // phase 1: load this batch's targets
    if (t < N_) {
        const float* tg = targets + (b * N_ + t) * 3;
        const float tl = tg[0], tr = tg[1];
        tl0[t] = tl; tr0[t] = tr; lb0[t] = tg[2];
        ar0[t] = (tr - tl) * 256.0f;
    }
    __syncthreads();

    // phase 2: stable rank-sort segments by area (tie: orig index) + ep build
    if (t < N_) {
        const float an = ar0[t];
        int r = 0;
        #pragma unroll
        for (int m = 0; m < N_; ++m) {
            const float am = ar0[m];
            r += (am < an) || (am == an && m < t);
        }
        stl[r] = tl0[t]; str[r] = tr0[t]; slb[r] = lb0[t];
    }
    if (t < NE) s_ep[t] = (t < N_) ? tl0[t] : tr0[t - N_];
    __syncthreads();

    // phase 3: rank-sort endpoints
    if (t < NE) {
        const float v = s_ep[t];
        int r = 0;
        #pragma unroll
        for (int m = 0; m < NE; ++m) {
            const float vm = s_ep[m];
            r += (vm < v) || (vm == v && m < t);
        }
        s_bp[r] = v;
    }
    __syncthreads();

    // phase 4: winner tables + range ballot (one phase, one barrier)
    if (t < 128) {
        const float v = (t < NE) ? s_bp[t] : INFINITY;
        const float cmin = priors[kb];              // uniform
        const float cmax = priors[kend - 1];
        const unsigned long long mlo = __ballot(v < cmin);
        const unsigned long long mhi = __ballot(v <= cmax);
        const int wv = t >> 6;                       // 0 or 1
        if ((t & 63) == 0) {
            s_cnt[wv]     = __popcll(mlo);
            s_cnt[2 + wv] = __popcll(mhi);
        }
    }
    if (t < NE) {                                    // point winners
        const float v = s_bp[t];
        int w = N_;
        for (int s = N_ - 1; s >= 0; --s)
            w = (stl[s] <= v && v <= str[s]) ? s : w;
        const bool ok = (w < N_);
        const int si = ok ? w : 0;
        s_tab[t] = ok ? make_float4(stl[si], str[si], slb[si], 1.0f)
                      : make_float4(0.f, 0.f, 0.f, 0.f);
    }
    if (t >= 128 && t < 128 + NE + 1) {              // gap winners
        const int g = t - 128;                       // 0..80
        const float a  = g ? s_bp[g - 1] : -INFINITY;
        const float bb = (g < NE) ? s_bp[g] : INFINITY;
        int w = N_;
        for (int s = N_ - 1; s >= 0; --s)
            w = (stl[s] <= a && bb <= str[s]) ? s : w;
        const bool ok = (w < N_);
        const int si = ok ? w : 0;
        s_tab[NE + g] = ok ? make_float4(stl[si], str[si], slb[si], 1.0f)
                           : make_float4(0.f, 0.f, 0.f, 0.f);
    }
    __syncthreads();

    const int base = s_cnt[0] + s_cnt[1];            // #bp <  cmin
    const int end  = s_cnt[2] + s_cnt[3];            // #bp <= cmax

    // ======== compute: loop-carried 1-deep register prefetch ========
    const int bK  = b * K_;
    const int bK2 = bK * 2;

    float f0 = 0.f, f1 = 0.f, f2 = 0.f, f3 = 0.f, f4 = 0.f, f5 = 0.f, f6 = 0.f;

    int  k  = kb + t;
    bool vc = (k < kend);
    float2 lc, cc_, pc_, qc; float gc, rc;
    if (vc) {
        const int i2 = bK2 + k * 2;
        lc  = *(const float2*)(loc   + i2);
        cc_ = *(const float2*)(conf  + i2);
        pc_ = *(const float2*)(ploc  + i2);
        qc  = *(const float2*)(pconf + i2);
        gc  = center[bK + k];
        rc  = priors[k];
    }
    #pragma unroll
    for (int it = 0; it < NITER; ++it) {
        // prefetch next item (6 independent loads, ~12 regs in flight)
        const int  kn = k + TPB;
        const bool vn = (it < NITER - 1) && (kn < kend);
        float2 ln, cn, pn, qn; float gn, rn;
        if (vn) {
            const int i2n = bK2 + kn * 2;
            ln = *(const float2*)(loc   + i2n);
            cn = *(const float2*)(conf  + i2n);
            pn = *(const float2*)(ploc  + i2n);
            qn = *(const float2*)(pconf + i2n);
            gn = center[bK + kn];
            rn = priors[kn];
        }
        // compute current item while next item's loads are in flight
        if (vc)
            elem_accum(rc, lc.x, lc.y, cc_.x, cc_.y,
                       pc_.x, pc_.y, qc.x, qc.y, gc,
                       base, end, s_bp, s_tab,
                       f0, f1, f2, f3, f4, f5, f6);
        lc = ln; cc_ = cn; pc_ = pn; qc = qn; gc = gn; rc = rn;
        k = kn; vc = vn;
    }

    // ---- block reduction (f32 wave tree, f64 cross-wave) -> partials ----
    {
        float vals[NACC] = {f0, f1, f2, f3, f4, f5, f6};
        const int wave = t >> 6, lane = t & 63;
        #pragma unroll
        for (int q = 0; q < NACC; ++q) {
            float v = vals[q];
            #pragma unroll
            for (int off = 32; off > 0; off >>= 1)
                v += __shfl_down(v, off, 64);
            if (lane == 0) s_redf[wave][q] = v;
        }
    }
    __syncthreads();
    if (t == 0) {
        float* partials = (float*)ws;
        const int bid = b * CBX + cb;
        #pragma unroll
        for (int q = 0; q < NACC; ++q) {
            double s = 0.0;
            #pragma unroll
            for (int w2 = 0; w2 < TPB / 64; ++w2) s += (double)s_redf[w2][q];
            partials[bid * PACC + q] = (float)s;
        }
    }
}

__global__ __launch_bounds__(TPB) void msl_final(
    const float* __restrict__ partials, float* __restrict__ out)
{
    __shared__ double s_red[TPB / 64][NACC];
    double acc[NACC] = {0, 0, 0, 0, 0, 0, 0};
    for (int i = threadIdx.x; i < NBLOCKS; i += TPB) {
        #pragma unroll
        for (int q = 0; q < NACC; ++q)
            acc[q] += (double)partials[i * PACC + q];
    }
    const int wave = threadIdx.x >> 6, lane = threadIdx.x & 63;
    #pragma unroll
    for (int q = 0; q < NACC; ++q) {
        double v = acc[q];
        #pragma unroll
        for (int off = 32; off > 0; off >>= 1)
            v += __shfl_down(v, off, 64);
        if (lane == 0) s_red[wave][q] = v;
    }
    __syncthreads();
    if (threadIdx.x == 0) {
        double s[NACC];
        #pragma unroll
        for (int q = 0; q < NACC; ++q) {
            double v = 0.0;
            #pragma unroll
            for (int w = 0; w < TPB / 64; ++w) v += s_red[w][q];
            s[q] = v;
        }
        const double Np = fmax(s[5], 1.0);
        const double PN = fmax(s[6], 1.0);
        out[0] = (float)(s[0] / Np);
        out[1] = (float)(s[1] / Np);
        out[2] = (float)(s[2] / PN);
        out[3] = (float)(s[3] / PN);
        out[4] = (float)(s[4] / Np);
    }
}

extern "C" void kernel_launch(void* const* d_in, const int* in_sizes, int n_in,
                              void* d_out, int out_size, void* d_ws, size_t ws_size,
                              hipStream_t stream) {
    const float* loc     = (const float*)d_in[0];
    const float* conf    = (const float*)d_in[1];
    const float* ploc    = (const float*)d_in[2];
    const float* pconf   = (const float*)d_in[3];
    const float* center  = (const float*)d_in[4];
    const float* priors  = (const float*)d_in[5];
    const float* targets = (const float*)d_in[6];
    char* ws = (char*)d_ws;   // uses 65,536 bytes (partials only)

    dim3 grid(CBX, B_);
    msl_main<<<grid, TPB, 0, stream>>>(loc, conf, ploc, pconf, center, priors,
                                       targets, ws);
    msl_final<<<1, TPB, 0, stream>>>((const float*)ws, (float*)d_out);
}